// Round 1
// baseline (845.327 us; speedup 1.0000x reference)
//
#include <hip/hip_runtime.h>
#include <math.h>

#define N     4096
#define DC    14
#define KCAT  336
#define KX    384      // padded combined: [cont 0..13][pad 14..15][cat 16..351][pad 352..383]
#define DF    512
#define TILE  64
#define KC    64
#define LDT   68       // padded LDS leading dim: 68*4B = 272B = 16B-aligned rows

// ws layout (float offsets)
#define XC_OFF   0
#define FH_OFF   (N*KX)                 // 1,572,864
#define RM_OFF   (FH_OFF + N*DF)        // 3,670,016
#define POS_OFF  (RM_OFF + N)
#define DEN_OFF  (POS_OFF + N)
#define CSQ_OFF  (DEN_OFF + N)
#define WS_FLOATS (CSQ_OFF + N)         // ~3.69M floats = ~14.1 MB

__global__ __launch_bounds__(64) void prep_kernel(
    const float* __restrict__ feat, const float* __restrict__ cont,
    const float* __restrict__ cat, float* __restrict__ ws) {
  int i = blockIdx.x;
  int t = threadIdx.x;
  float* Xc   = ws + XC_OFF;
  float* fhat = ws + FH_OFF;

  // feature row norm (512 = 8 * 64)
  float fv[8];
  float s = 0.f;
  #pragma unroll
  for (int r = 0; r < 8; ++r) { fv[r] = feat[i*DF + r*64 + t]; s += fv[r]*fv[r]; }
  #pragma unroll
  for (int off = 32; off > 0; off >>= 1) s += __shfl_down(s, off);
  s = __shfl(s, 0);
  float inv = 1.0f / sqrtf(s);
  #pragma unroll
  for (int r = 0; r < 8; ++r) fhat[i*DF + r*64 + t] = fv[r] * inv;

  // continuous squared norm
  float cv = (t < DC) ? cont[i*DC + t] : 0.f;
  float cs = cv * cv;
  #pragma unroll
  for (int off = 32; off > 0; off >>= 1) cs += __shfl_down(cs, off);
  cs = __shfl(cs, 0);

  // padded combined matrix
  #pragma unroll
  for (int r = 0; r < 6; ++r) {
    int k = r*64 + t;
    float v = 0.f;
    if (k < DC) v = cont[i*DC + k];
    else if (k >= 16 && k < 16 + KCAT) v = cat[i*KCAT + (k - 16)];
    Xc[i*KX + k] = v;
  }

  if (t == 0) {
    ws[RM_OFF  + i] = 0.f;   // rowmax init: diagonal contributes 0, so true max >= 0
    ws[POS_OFF + i] = 0.f;
    ws[DEN_OFF + i] = 0.f;
    ws[CSQ_OFF + i] = cs;
  }
}

// load a 64-row x 64-k tile of G (leading dim ldg) into S transposed: S[k][row]
__device__ __forceinline__ void load_tile_T(const float* __restrict__ G, int row0,
                                            int ldg, int kb, float (*S)[LDT], int t) {
  #pragma unroll
  for (int rep = 0; rep < 4; ++rep) {
    int f  = t + rep*256;
    int r  = f >> 4;
    int kq = (f & 15) << 2;
    const float4 v = *(const float4*)&G[(size_t)(row0 + r)*ldg + kb + kq];
    S[kq+0][r] = v.x; S[kq+1][r] = v.y; S[kq+2][r] = v.z; S[kq+3][r] = v.w;
  }
}

__device__ __forceinline__ void fma_tile(const float (*As)[LDT], const float (*Bs)[LDT],
                                         int kk, int ty, int tx, float (*acc)[4]) {
  float4 a = *(const float4*)&As[kk][ty << 2];
  float4 b = *(const float4*)&Bs[kk][tx << 2];
  float ar[4] = {a.x, a.y, a.z, a.w};
  float br[4] = {b.x, b.y, b.z, b.w};
  #pragma unroll
  for (int r = 0; r < 4; ++r)
    #pragma unroll
    for (int c = 0; c < 4; ++c)
      acc[r][c] += ar[r] * br[c];
}

// Pass 1: sim tile -> per-row max
__global__ __launch_bounds__(256) void simmax_kernel(float* ws, const int* __restrict__ lcp) {
  __shared__ float As[KC][LDT];
  __shared__ float Bs[KC][LDT];
  const float* Xc  = ws + XC_OFF;
  const float* csq = ws + CSQ_OFF;
  int t  = threadIdx.x;
  int tx = t & 15, ty = t >> 4;
  int i0 = blockIdx.y * TILE, j0 = blockIdx.x * TILE;

  float accc[4][4] = {{0.f}}, acat[4][4] = {{0.f}};
  for (int kb = 0; kb < KX; kb += KC) {
    load_tile_T(Xc, i0, KX, kb, As, t);
    load_tile_T(Xc, j0, KX, kb, Bs, t);
    __syncthreads();
    int kstart = 0;
    if (kb == 0) {
      #pragma unroll
      for (int kk = 0; kk < 16; ++kk) fma_tile(As, Bs, kk, ty, tx, accc);
      kstart = 16;
    }
    for (int kk = kstart; kk < KC; ++kk) fma_tile(As, Bs, kk, ty, tx, acat);
    __syncthreads();
  }

  float lcf = (float)(*lcp);
  float csi[4], csj[4];
  #pragma unroll
  for (int r = 0; r < 4; ++r) csi[r] = csq[i0 + (ty<<2) + r];
  #pragma unroll
  for (int c = 0; c < 4; ++c) csj[c] = csq[j0 + (tx<<2) + c];

  #pragma unroll
  for (int r = 0; r < 4; ++r) {
    int gi = i0 + (ty<<2) + r;
    float rmax = -1e30f;
    #pragma unroll
    for (int c = 0; c < 4; ++c) {
      int gj = j0 + (tx<<2) + c;
      float d2   = fmaxf(csi[r] + csj[c] - 2.f*accc[r][c], 0.f);
      float csim = 1.0f / (1.0f + sqrtf(d2)) * 2.0f - 1.0f;
      float sim  = 0.5f*csim + 0.5f*(acat[r][c] / lcf);
      if (gi == gj) sim = 0.f;
      rmax = fmaxf(rmax, sim);
    }
    #pragma unroll
    for (int off = 1; off < 16; off <<= 1) rmax = fmaxf(rmax, __shfl_xor(rmax, off));
    if (tx == 0) atomicMax((int*)(ws + RM_OFF + gi), __float_as_int(rmax));
  }
}

// Pass 2: recompute sim -> mask; fhat gram -> exp; accumulate pos/den
__global__ __launch_bounds__(256) void loss_kernel(float* ws, const int* __restrict__ lcp) {
  __shared__ float As[KC][LDT];
  __shared__ float Bs[KC][LDT];
  const float* Xc     = ws + XC_OFF;
  const float* fh     = ws + FH_OFF;
  const float* csq    = ws + CSQ_OFF;
  const float* rowmax = ws + RM_OFF;
  int t  = threadIdx.x;
  int tx = t & 15, ty = t >> 4;
  int i0 = blockIdx.y * TILE, j0 = blockIdx.x * TILE;

  float acc1[4][4] = {{0.f}}, acc2[4][4] = {{0.f}};
  // phase A: sim accumulators (acc1 = cont dot, acc2 = cat dot)
  for (int kb = 0; kb < KX; kb += KC) {
    load_tile_T(Xc, i0, KX, kb, As, t);
    load_tile_T(Xc, j0, KX, kb, Bs, t);
    __syncthreads();
    int kstart = 0;
    if (kb == 0) {
      #pragma unroll
      for (int kk = 0; kk < 16; ++kk) fma_tile(As, Bs, kk, ty, tx, acc1);
      kstart = 16;
    }
    for (int kk = kstart; kk < KC; ++kk) fma_tile(As, Bs, kk, ty, tx, acc2);
    __syncthreads();
  }

  float lcf = (float)(*lcp);
  float csi[4], csj[4], rmx[4];
  #pragma unroll
  for (int r = 0; r < 4; ++r) { csi[r] = csq[i0 + (ty<<2) + r]; rmx[r] = rowmax[i0 + (ty<<2) + r] - 0.05f; }
  #pragma unroll
  for (int c = 0; c < 4; ++c) csj[c] = csq[j0 + (tx<<2) + c];

  unsigned mask = 0;
  #pragma unroll
  for (int r = 0; r < 4; ++r) {
    int gi = i0 + (ty<<2) + r;
    #pragma unroll
    for (int c = 0; c < 4; ++c) {
      int gj = j0 + (tx<<2) + c;
      float d2   = fmaxf(csi[r] + csj[c] - 2.f*acc1[r][c], 0.f);
      float csim = 1.0f / (1.0f + sqrtf(d2)) * 2.0f - 1.0f;
      float sim  = 0.5f*csim + 0.5f*(acc2[r][c] / lcf);
      if (gi == gj) sim = 0.f;
      if (sim >= rmx[r]) mask |= (1u << (r*4 + c));
    }
  }

  // phase B: normalized-feature gram
  #pragma unroll
  for (int r = 0; r < 4; ++r)
    #pragma unroll
    for (int c = 0; c < 4; ++c) acc1[r][c] = 0.f;
  for (int kb = 0; kb < DF; kb += KC) {
    load_tile_T(fh, i0, DF, kb, As, t);
    load_tile_T(fh, j0, DF, kb, Bs, t);
    __syncthreads();
    #pragma unroll
    for (int kk = 0; kk < KC; ++kk) fma_tile(As, Bs, kk, ty, tx, acc1);
    __syncthreads();
  }

  #pragma unroll
  for (int r = 0; r < 4; ++r) {
    int gi = i0 + (ty<<2) + r;
    float posp = 0.f, denp = 0.f;
    #pragma unroll
    for (int c = 0; c < 4; ++c) {
      float e = __expf(acc1[r][c] * 10.0f);
      denp += e;
      if (mask & (1u << (r*4 + c))) posp += e;
    }
    #pragma unroll
    for (int off = 1; off < 16; off <<= 1) {
      posp += __shfl_xor(posp, off);
      denp += __shfl_xor(denp, off);
    }
    if (tx == 0) {
      atomicAdd(ws + POS_OFF + gi, posp);
      atomicAdd(ws + DEN_OFF + gi, denp);
    }
  }
}

__global__ __launch_bounds__(256) void reduce_kernel(const float* __restrict__ ws, float* __restrict__ out) {
  __shared__ float sred[4];
  int t = threadIdx.x;
  float s = 0.f;
  for (int i = t; i < N; i += 256) {
    float p = ws[POS_OFF + i], d = ws[DEN_OFF + i];
    s += -logf(p / d);
  }
  #pragma unroll
  for (int off = 32; off > 0; off >>= 1) s += __shfl_down(s, off);
  if ((t & 63) == 0) sred[t >> 6] = s;
  __syncthreads();
  if (t == 0) out[0] = (sred[0] + sred[1] + sred[2] + sred[3]) * (1.0f / N);
}

extern "C" void kernel_launch(void* const* d_in, const int* in_sizes, int n_in,
                              void* d_out, int out_size, void* d_ws, size_t ws_size,
                              hipStream_t stream) {
  (void)in_sizes; (void)n_in; (void)out_size; (void)ws_size;
  const float* feat = (const float*)d_in[0];
  const float* cont = (const float*)d_in[1];
  const float* cat  = (const float*)d_in[2];
  const int*   lc   = (const int*)d_in[3];
  float* ws  = (float*)d_ws;
  float* out = (float*)d_out;

  prep_kernel<<<N, 64, 0, stream>>>(feat, cont, cat, ws);
  dim3 grid(N / TILE, N / TILE);
  simmax_kernel<<<grid, 256, 0, stream>>>(ws, lc);
  loss_kernel<<<grid, 256, 0, stream>>>(ws, lc);
  reduce_kernel<<<1, 256, 0, stream>>>(ws, out);
}

// Round 3
// 349.537 us; speedup vs baseline: 2.4184x; 2.4184x over previous
//
#include <hip/hip_runtime.h>
#include <math.h>

#define NN    4096
#define DCC   14
#define KCATN 336
#define KXP   384      // [cont 0..13][pad..31][cat 32..367][pad..383]
#define DF    512
#define NT    32       // 4096 / 128 tiles per dim
#define NTRI  528      // NT*(NT+1)/2

typedef __attribute__((ext_vector_type(4))) float f32x4;
typedef __attribute__((ext_vector_type(8))) short short8;
typedef unsigned short ushort_t;
typedef unsigned long long u64;

__device__ __forceinline__ f32x4 mfma16(short8 a, short8 b, f32x4 c) {
  return __builtin_amdgcn_mfma_f32_16x16x32_bf16(a, b, c, 0, 0, 0);
}
__device__ __forceinline__ short8 ld8(const ushort_t* p) {
  return *(const short8*)p;
}
__device__ __forceinline__ ushort_t f2bf(float x) {
  unsigned u = __float_as_uint(x);
  return (ushort_t)((u + 0x7fffu + ((u >> 16) & 1u)) >> 16);
}
__device__ __forceinline__ float bf2f(ushort_t u) {
  return __uint_as_float(((unsigned)u) << 16);
}
__device__ __forceinline__ float sim_of(float cdot, float kdot, float si, float sj, float invl) {
  float d2 = fmaxf(si + sj - 2.f * cdot, 0.f);
  float cs = 1.0f / (1.0f + sqrtf(d2)) * 2.0f - 1.0f;
  return 0.5f * cs + 0.5f * (kdot * invl);
}

// one K=32 gram step: split-bf16, 3 products into same fp32 acc
__device__ __forceinline__ void gram_step(const ushort_t* pah, const ushort_t* pal,
                                          const ushort_t* pbh, const ushort_t* pbl,
                                          int ldr, int koff, f32x4 (*acc)[4]) {
  short8 ah[4], al[4], bh[4], bl[4];
  #pragma unroll
  for (int f = 0; f < 4; ++f) {
    const int ro = f * 16 * ldr + koff;
    ah[f] = ld8(pah + ro); al[f] = ld8(pal + ro);
    bh[f] = ld8(pbh + ro); bl[f] = ld8(pbl + ro);
  }
  #pragma unroll
  for (int mf = 0; mf < 4; ++mf)
    #pragma unroll
    for (int nf = 0; nf < 4; ++nf) {
      acc[mf][nf] = mfma16(ah[mf], bh[nf], acc[mf][nf]);
      acc[mf][nf] = mfma16(ah[mf], bl[nf], acc[mf][nf]);
      acc[mf][nf] = mfma16(al[mf], bh[nf], acc[mf][nf]);
    }
}

__device__ __forceinline__ void tri_map(int t, int* bip, int* bjp) {
  int bi = 0, rem = t;
  while (rem >= NT - bi) { rem -= NT - bi; ++bi; }
  *bip = bi; *bjp = bi + rem;
}

__global__ __launch_bounds__(64) void prep_kernel(
    const float* __restrict__ feat, const float* __restrict__ cont,
    const float* __restrict__ cat,
    ushort_t* __restrict__ fhh, ushort_t* __restrict__ fhl,
    ushort_t* __restrict__ xch, ushort_t* __restrict__ xcl,
    float* __restrict__ csq, float* __restrict__ rm,
    float* __restrict__ pos, float* __restrict__ den) {
  int i = blockIdx.x;
  int t = threadIdx.x;

  // normalized features -> bf16 hi/lo
  float fv[8];
  float s = 0.f;
  #pragma unroll
  for (int r = 0; r < 8; ++r) { fv[r] = feat[i * DF + r * 64 + t]; s += fv[r] * fv[r]; }
  #pragma unroll
  for (int off = 32; off > 0; off >>= 1) s += __shfl_down(s, off);
  s = __shfl(s, 0);
  float inv = 1.0f / sqrtf(s);
  #pragma unroll
  for (int r = 0; r < 8; ++r) {
    float x = fv[r] * inv;
    ushort_t h = f2bf(x);
    fhh[i * DF + r * 64 + t] = h;
    fhl[i * DF + r * 64 + t] = f2bf(x - bf2f(h));
  }

  // continuous squared norm
  float cv = (t < DCC) ? cont[i * DCC + t] : 0.f;
  float cs = cv * cv;
  #pragma unroll
  for (int off = 32; off > 0; off >>= 1) cs += __shfl_down(cs, off);
  cs = __shfl(cs, 0);

  // padded combined matrix -> bf16 hi/lo
  #pragma unroll
  for (int r = 0; r < 6; ++r) {
    int k = r * 64 + t;
    float v = 0.f;
    if (k < DCC) v = cont[i * DCC + k];
    else if (k >= 32 && k < 32 + KCATN) v = cat[i * KCATN + (k - 32)];
    ushort_t h = f2bf(v);
    xch[i * KXP + k] = h;
    xcl[i * KXP + k] = f2bf(v - bf2f(h));
  }

  if (t == 0) {
    csq[i] = cs;
    rm[i] = 0.f;   // diag sim = 0 -> true rowmax >= 0
    pos[i] = 0.f;
    den[i] = 0.f;
  }
}

// Pass A: sim tiles (triangular) -> per-row max (row-side + mirrored col-side)
__global__ __launch_bounds__(256, 2) void passA_kernel(
    const ushort_t* __restrict__ xch, const ushort_t* __restrict__ xcl,
    const float* __restrict__ csq, float* __restrict__ rm,
    const int* __restrict__ lcp) {
  int bi, bj; tri_map(blockIdx.x, &bi, &bj);
  const int tid = threadIdx.x;
  const int lane = tid & 63, w = tid >> 6;
  const int wm = w >> 1, wn = w & 1;
  const int l15 = lane & 15, lg = lane >> 4;
  const int i0 = bi * 128 + wm * 64, j0 = bj * 128 + wn * 64;

  const ushort_t* pah = xch + (size_t)(i0 + l15) * KXP + lg * 8;
  const ushort_t* pal = xcl + (size_t)(i0 + l15) * KXP + lg * 8;
  const ushort_t* pbh = xch + (size_t)(j0 + l15) * KXP + lg * 8;
  const ushort_t* pbl = xcl + (size_t)(j0 + l15) * KXP + lg * 8;

  f32x4 accC[4][4], accK[4][4];
  #pragma unroll
  for (int a = 0; a < 4; ++a)
    #pragma unroll
    for (int b = 0; b < 4; ++b) { accC[a][b] = (f32x4){0.f,0.f,0.f,0.f}; accK[a][b] = (f32x4){0.f,0.f,0.f,0.f}; }

  gram_step(pah, pal, pbh, pbl, KXP, 0, accC);          // cont block (k 0..31)
  for (int kb = 1; kb < 12; ++kb)
    gram_step(pah, pal, pbh, pbl, KXP, kb * 32, accK);  // cat blocks

  const float invl = 1.0f / (float)(*lcp);
  float csqi[4][4], csqj[4];
  #pragma unroll
  for (int mf = 0; mf < 4; ++mf)
    #pragma unroll
    for (int r = 0; r < 4; ++r) csqi[mf][r] = csq[i0 + mf * 16 + lg * 4 + r];
  #pragma unroll
  for (int nf = 0; nf < 4; ++nf) csqj[nf] = csq[j0 + nf * 16 + l15];

  float rmaxr[4][4], cmax[4];
  #pragma unroll
  for (int mf = 0; mf < 4; ++mf)
    #pragma unroll
    for (int r = 0; r < 4; ++r) rmaxr[mf][r] = -1e30f;
  #pragma unroll
  for (int nf = 0; nf < 4; ++nf) cmax[nf] = -1e30f;

  #pragma unroll
  for (int mf = 0; mf < 4; ++mf)
    #pragma unroll
    for (int nf = 0; nf < 4; ++nf)
      #pragma unroll
      for (int r = 0; r < 4; ++r) {
        int gi = i0 + mf * 16 + lg * 4 + r;
        int gj = j0 + nf * 16 + l15;
        float sim = sim_of(accC[mf][nf][r], accK[mf][nf][r], csqi[mf][r], csqj[nf], invl);
        if (gi == gj) sim = 0.f;
        rmaxr[mf][r] = fmaxf(rmaxr[mf][r], sim);
        cmax[nf] = fmaxf(cmax[nf], sim);
      }

  // row-side: reduce over 16 cols (lanes l15)
  #pragma unroll
  for (int mf = 0; mf < 4; ++mf)
    #pragma unroll
    for (int r = 0; r < 4; ++r) {
      float v = rmaxr[mf][r];
      #pragma unroll
      for (int off = 1; off < 16; off <<= 1) v = fmaxf(v, __shfl_xor(v, off));
      if (l15 == 0) atomicMax((int*)&rm[i0 + mf * 16 + lg * 4 + r], __float_as_int(v));
    }
  // col-side (mirror): reduce over rows (lane groups)
  if (bi != bj) {
    #pragma unroll
    for (int nf = 0; nf < 4; ++nf) {
      float v = cmax[nf];
      v = fmaxf(v, __shfl_xor(v, 16));
      v = fmaxf(v, __shfl_xor(v, 32));
      if (lg == 0) atomicMax((int*)&rm[j0 + nf * 16 + l15], __float_as_int(v));
    }
  }
}

// Pass B: recompute sim -> masks; f-gram -> exp; pos/den (row-side + mirror)
__global__ __launch_bounds__(256, 2) void passB_kernel(
    const ushort_t* __restrict__ xch, const ushort_t* __restrict__ xcl,
    const ushort_t* __restrict__ fhh, const ushort_t* __restrict__ fhl,
    const float* __restrict__ csq, const float* __restrict__ rm,
    float* __restrict__ pos, float* __restrict__ den,
    const int* __restrict__ lcp) {
  int bi, bj; tri_map(blockIdx.x, &bi, &bj);
  const int tid = threadIdx.x;
  const int lane = tid & 63, w = tid >> 6;
  const int wm = w >> 1, wn = w & 1;
  const int l15 = lane & 15, lg = lane >> 4;
  const int i0 = bi * 128 + wm * 64, j0 = bj * 128 + wn * 64;

  // ---- sim grams ----
  {
    const ushort_t* pah = xch + (size_t)(i0 + l15) * KXP + lg * 8;
    const ushort_t* pal = xcl + (size_t)(i0 + l15) * KXP + lg * 8;
    const ushort_t* pbh = xch + (size_t)(j0 + l15) * KXP + lg * 8;
    const ushort_t* pbl = xcl + (size_t)(j0 + l15) * KXP + lg * 8;

    f32x4 accC[4][4], accK[4][4];
    #pragma unroll
    for (int a = 0; a < 4; ++a)
      #pragma unroll
      for (int b = 0; b < 4; ++b) { accC[a][b] = (f32x4){0.f,0.f,0.f,0.f}; accK[a][b] = (f32x4){0.f,0.f,0.f,0.f}; }

    gram_step(pah, pal, pbh, pbl, KXP, 0, accC);
    for (int kb = 1; kb < 12; ++kb)
      gram_step(pah, pal, pbh, pbl, KXP, kb * 32, accK);

    const float invl = 1.0f / (float)(*lcp);
    float csqi[4][4], csqj[4], rmi[4][4], rmj[4];
    #pragma unroll
    for (int mf = 0; mf < 4; ++mf)
      #pragma unroll
      for (int r = 0; r < 4; ++r) {
        int gi = i0 + mf * 16 + lg * 4 + r;
        csqi[mf][r] = csq[gi];
        rmi[mf][r] = rm[gi] - 0.05f;
      }
    #pragma unroll
    for (int nf = 0; nf < 4; ++nf) {
      int gj = j0 + nf * 16 + l15;
      csqj[nf] = csq[gj];
      rmj[nf] = rm[gj] - 0.05f;
    }

    u64 mA = 0, mB = 0;
    #pragma unroll
    for (int mf = 0; mf < 4; ++mf)
      #pragma unroll
      for (int nf = 0; nf < 4; ++nf)
        #pragma unroll
        for (int r = 0; r < 4; ++r) {
          int gi = i0 + mf * 16 + lg * 4 + r;
          int gj = j0 + nf * 16 + l15;
          float sim = sim_of(accC[mf][nf][r], accK[mf][nf][r], csqi[mf][r], csqj[nf], invl);
          if (gi == gj) sim = 0.f;
          u64 bit = 1ull << (mf * 16 + nf * 4 + r);
          if (sim >= rmi[mf][r]) mA |= bit;
          if (sim >= rmj[nf]) mB |= bit;
        }

    // ---- f-gram ----
    const ushort_t* qah = fhh + (size_t)(i0 + l15) * DF + lg * 8;
    const ushort_t* qal = fhl + (size_t)(i0 + l15) * DF + lg * 8;
    const ushort_t* qbh = fhh + (size_t)(j0 + l15) * DF + lg * 8;
    const ushort_t* qbl = fhl + (size_t)(j0 + l15) * DF + lg * 8;

    f32x4 facc[4][4];
    #pragma unroll
    for (int a = 0; a < 4; ++a)
      #pragma unroll
      for (int b = 0; b < 4; ++b) facc[a][b] = (f32x4){0.f,0.f,0.f,0.f};
    for (int kb = 0; kb < 16; ++kb)
      gram_step(qah, qal, qbh, qbl, DF, kb * 32, facc);

    // ---- epilogue ----
    float posA[4][4], denA[4][4], posB[4], denB[4];
    #pragma unroll
    for (int mf = 0; mf < 4; ++mf)
      #pragma unroll
      for (int r = 0; r < 4; ++r) { posA[mf][r] = 0.f; denA[mf][r] = 0.f; }
    #pragma unroll
    for (int nf = 0; nf < 4; ++nf) { posB[nf] = 0.f; denB[nf] = 0.f; }

    #pragma unroll
    for (int mf = 0; mf < 4; ++mf)
      #pragma unroll
      for (int nf = 0; nf < 4; ++nf)
        #pragma unroll
        for (int r = 0; r < 4; ++r) {
          float e = __expf(facc[mf][nf][r] * 10.0f);
          denA[mf][r] += e;
          denB[nf] += e;
          u64 bit = 1ull << (mf * 16 + nf * 4 + r);
          if (mA & bit) posA[mf][r] += e;
          if (mB & bit) posB[nf] += e;
        }

    #pragma unroll
    for (int mf = 0; mf < 4; ++mf)
      #pragma unroll
      for (int r = 0; r < 4; ++r) {
        float p = posA[mf][r], d = denA[mf][r];
        #pragma unroll
        for (int off = 1; off < 16; off <<= 1) { p += __shfl_xor(p, off); d += __shfl_xor(d, off); }
        if (l15 == 0) {
          int gi = i0 + mf * 16 + lg * 4 + r;
          atomicAdd(&pos[gi], p);
          atomicAdd(&den[gi], d);
        }
      }
    if (bi != bj) {
      #pragma unroll
      for (int nf = 0; nf < 4; ++nf) {
        float p = posB[nf], d = denB[nf];
        p += __shfl_xor(p, 16); d += __shfl_xor(d, 16);
        p += __shfl_xor(p, 32); d += __shfl_xor(d, 32);
        if (lg == 0) {
          int gj = j0 + nf * 16 + l15;
          atomicAdd(&pos[gj], p);
          atomicAdd(&den[gj], d);
        }
      }
    }
  }
}

__global__ __launch_bounds__(256) void reduce_kernel(const float* __restrict__ pos,
                                                     const float* __restrict__ den,
                                                     float* __restrict__ out) {
  __shared__ float sred[4];
  int t = threadIdx.x;
  float s = 0.f;
  for (int i = t; i < NN; i += 256) s += -logf(pos[i] / den[i]);
  #pragma unroll
  for (int off = 32; off > 0; off >>= 1) s += __shfl_down(s, off);
  if ((t & 63) == 0) sred[t >> 6] = s;
  __syncthreads();
  if (t == 0) out[0] = (sred[0] + sred[1] + sred[2] + sred[3]) * (1.0f / NN);
}

extern "C" void kernel_launch(void* const* d_in, const int* in_sizes, int n_in,
                              void* d_out, int out_size, void* d_ws, size_t ws_size,
                              hipStream_t stream) {
  (void)in_sizes; (void)n_in; (void)out_size; (void)ws_size;
  const float* feat = (const float*)d_in[0];
  const float* cont = (const float*)d_in[1];
  const float* cat  = (const float*)d_in[2];
  const int*   lc   = (const int*)d_in[3];
  float* out = (float*)d_out;

  // ws layout (14,745,600 bytes total, same as round-1 footprint)
  ushort_t* fhh = (ushort_t*)d_ws;
  ushort_t* fhl = fhh + (size_t)NN * DF;
  ushort_t* xch = fhl + (size_t)NN * DF;
  ushort_t* xcl = xch + (size_t)NN * KXP;
  float* csq = (float*)(xcl + (size_t)NN * KXP);
  float* rm  = csq + NN;
  float* pos = rm + NN;
  float* den = pos + NN;

  prep_kernel<<<NN, 64, 0, stream>>>(feat, cont, cat, fhh, fhl, xch, xcl, csq, rm, pos, den);
  passA_kernel<<<NTRI, 256, 0, stream>>>(xch, xcl, csq, rm, lc);
  passB_kernel<<<NTRI, 256, 0, stream>>>(xch, xcl, fhh, fhl, csq, rm, pos, den, lc);
  reduce_kernel<<<1, 256, 0, stream>>>(pos, den, out);
}